// Round 2
// 194.196 us; speedup vs baseline: 1.0857x; 1.0857x over previous
//
#include <hip/hip_runtime.h>
#include <hip/hip_bf16.h>

// AttentionBlock: GroupNorm(8) -> QKV 1x1 -> softmax attention (hw=1024, c=256) -> proj + residual
// B=32, C=256, H=W=32. Inputs fp32, OUTPUT fp32. Internals bf16 MFMA, fp32 accum.
// R11 = R10 resubmit (R10 bench was an infra container failure; source re-audited, no hang/fault
// candidate found). Changes vs R9:
//  - attn: T14 register prefetch of next K/V tile (issued right after staging barrier, lands
//    under QK+softmax phase) + s_setprio(1) around MFMA clusters. Structure otherwise identical.
//  - qkv/proj epilogues: C-tile staged through LDS (union with As/Bs -> no extra LDS),
//    then 64B-coalesced bf16x8/float4 global stores. Replaces 8B/4B scattered stores at 512B
//    stride (was ~64-128 VMEM instr/thread).
//  - wconv fused into gn_kernel (one fewer launch).
// ws: xnT 16MB | qtr 16MB | ktr 16MB | v 16MB | aoT 16MB | wbf 512KB.

typedef __bf16 bf16x8 __attribute__((ext_vector_type(8)));
typedef __bf16 bf16x4 __attribute__((ext_vector_type(4)));
typedef __bf16 bf16x2 __attribute__((ext_vector_type(2)));
typedef float f32x4 __attribute__((ext_vector_type(4)));
typedef float f32x16 __attribute__((ext_vector_type(16)));

#define MFMA16(a, b, c) __builtin_amdgcn_mfma_f32_16x16x32_bf16(a, b, c, 0, 0, 0)
#define MFMA32(a, b, c) __builtin_amdgcn_mfma_f32_32x32x16_bf16(a, b, c, 0, 0, 0)

// ---------------- K1: GroupNorm fp32 [b][c][s] -> bf16 xnT [b][s][c]  (+ fused weight convert) ----------------
__global__ __launch_bounds__(512) void gn_kernel(const float* __restrict__ x,
                                                 const float* __restrict__ gw,
                                                 const float* __restrict__ gb,
                                                 __bf16* __restrict__ xnT,
                                                 const float* __restrict__ wqkv,
                                                 const float* __restrict__ wout,
                                                 __bf16* __restrict__ wbf) {
    __shared__ float red[16];
    __shared__ float stats[2];
    __shared__ __bf16 Lds[512][40];
    const int b = blockIdx.x >> 3, g = blockIdx.x & 7;
    const size_t base = ((size_t)b * 256 + g * 32) * 1024;
    const float* xp = x + base;
    const int t = threadIdx.x;                // 0..511

    // fused wconv: 256 blocks * 512 thr * 2 floats = 262144 (wqkv 196608 | wout 65536)
    {
        int widx = (blockIdx.x * 512 + t) * 2;
        const float* wsrc = (widx < 196608) ? (wqkv + widx) : (wout + (widx - 196608));
        float2 wv = *(const float2*)wsrc;
        bf16x2 wo;
        wo[0] = (__bf16)wv.x; wo[1] = (__bf16)wv.y;
        *(bf16x2*)&wbf[widx] = wo;
    }

    float s = 0.f, s2 = 0.f;
    #pragma unroll
    for (int i = 0; i < 8; i++) {
        int j = i * 512 + t;                  // 8-elem chunk index
        float4 v0 = *(const float4*)(xp + (size_t)j * 8);
        float4 v1 = *(const float4*)(xp + (size_t)j * 8 + 4);
        s  += v0.x + v0.y + v0.z + v0.w + v1.x + v1.y + v1.z + v1.w;
        s2 += v0.x*v0.x + v0.y*v0.y + v0.z*v0.z + v0.w*v0.w
            + v1.x*v1.x + v1.y*v1.y + v1.z*v1.z + v1.w*v1.w;
    }
    #pragma unroll
    for (int o = 32; o > 0; o >>= 1) { s += __shfl_down(s, o, 64); s2 += __shfl_down(s2, o, 64); }
    const int wv = t >> 6;
    if ((t & 63) == 0) { red[wv * 2] = s; red[wv * 2 + 1] = s2; }
    __syncthreads();
    if (t == 0) {
        float ts = 0.f, ts2 = 0.f;
        for (int w = 0; w < 8; w++) { ts += red[w * 2]; ts2 += red[w * 2 + 1]; }
        float mean = ts / 32768.f;
        float var = ts2 / 32768.f - mean * mean;
        stats[0] = mean; stats[1] = rsqrtf(var + 1e-5f);
    }
    __syncthreads();
    const float mean = stats[0], inv = stats[1];

    const int c = t >> 4;                 // 0..31 channel within group
    const int so = (t & 15) * 2;          // s sub-offset (pairs)
    const float ga = gw[g * 32 + c], be = gb[g * 32 + c];

    for (int chunk = 0; chunk < 1024; chunk += 512) {
        #pragma unroll
        for (int i = 0; i < 16; i++) {
            int sl = so + i * 32;
            float2 v = *(const float2*)(xp + (size_t)c * 1024 + chunk + sl);
            Lds[sl][c]     = (__bf16)((v.x - mean) * inv * ga + be);
            Lds[sl + 1][c] = (__bf16)((v.y - mean) * inv * ga + be);
        }
        __syncthreads();
        {
            int sl = t;                   // one s-row per thread
            #pragma unroll
            for (int u = 0; u < 4; u++) {
                bf16x8 vv = *(const bf16x8*)&Lds[sl][u * 8];
                *(bf16x8*)&xnT[((size_t)b * 1024 + chunk + sl) * 256 + g * 32 + u * 8] = vv;
            }
        }
        __syncthreads();
    }
}

// ---------------- shared 128x128 GEMM body, BK=64, register-prefetch pipeline ----------------
// A = Wbf (bf16) rows m0.., B = src rows (b*1024+n0).., K=256 in 4 iters of 64.
#define GEMM64_BODY(ArowBase_, BrowBase_)                                               \
    f32x4 acc[4][4] = {};                                                               \
    const int r_ = t >> 1, kc_ = (t & 1) * 32;                                          \
    bf16x8 pa[4], pb[4];                                                                \
    _Pragma("unroll")                                                                   \
    for (int u = 0; u < 4; u++) {                                                       \
        pa[u] = *(const bf16x8*)&(ArowBase_)[(size_t)r_ * 256 + kc_ + u * 8];           \
        pb[u] = *(const bf16x8*)&(BrowBase_)[(size_t)r_ * 256 + kc_ + u * 8];           \
    }                                                                                   \
    for (int kk = 0; kk < 256; kk += 64) {                                              \
        _Pragma("unroll")                                                               \
        for (int u = 0; u < 4; u++) {                                                   \
            *(bf16x8*)&As[r_][kc_ + u * 8] = pa[u];                                     \
            *(bf16x8*)&Bs[r_][kc_ + u * 8] = pb[u];                                     \
        }                                                                               \
        __syncthreads();                                                                \
        if (kk < 192) {                                                                 \
            _Pragma("unroll")                                                           \
            for (int u = 0; u < 4; u++) {                                               \
                pa[u] = *(const bf16x8*)&(ArowBase_)[(size_t)r_ * 256 + kk + 64 + kc_ + u * 8]; \
                pb[u] = *(const bf16x8*)&(BrowBase_)[(size_t)r_ * 256 + kk + 64 + kc_ + u * 8]; \
            }                                                                           \
        }                                                                               \
        _Pragma("unroll")                                                               \
        for (int kh = 0; kh < 2; kh++) {                                                \
            bf16x8 af[4], bfv[4];                                                       \
            _Pragma("unroll")                                                           \
            for (int im = 0; im < 4; im++)                                              \
                af[im] = *(const bf16x8*)&As[wm + im * 16 + l16][kh * 32 + quad * 8];   \
            _Pragma("unroll")                                                           \
            for (int in = 0; in < 4; in++)                                              \
                bfv[in] = *(const bf16x8*)&Bs[wn + in * 16 + l16][kh * 32 + quad * 8];  \
            _Pragma("unroll")                                                           \
            for (int im = 0; im < 4; im++)                                              \
                _Pragma("unroll")                                                       \
                for (int in = 0; in < 4; in++)                                          \
                    acc[im][in] = MFMA16(af[im], bfv[in], acc[im][in]);                 \
        }                                                                               \
        __syncthreads();                                                                \
    }

// ---------------- K2: QKV GEMM, 128x128 tiles, bf16 weights, LDS-transposed epilogue ----------------
__global__ __launch_bounds__(256) void qkv_gemm(const __bf16* __restrict__ wbf,
                                                const float* __restrict__ bias,
                                                const __bf16* __restrict__ xnT,
                                                __bf16* __restrict__ qtr,
                                                __bf16* __restrict__ ktr,
                                                __bf16* __restrict__ vbuf) {
    __shared__ union {
        struct { __bf16 A[128][72]; __bf16 B[128][72]; } g;   // 36864 B main loop
        __bf16 ct[128][136];                                  // 34816 B epilogue [s][c]
    } sm;
    const int b = blockIdx.z;
    const int n0 = blockIdx.x * 128, m0 = blockIdx.y * 128;
    const int t = threadIdx.x;
    const int wave = t >> 6, lane = t & 63, quad = lane >> 4, l16 = lane & 15;
    const int wm = (wave & 1) * 64, wn = (wave >> 1) * 64;
    const __bf16* arow = wbf + (size_t)m0 * 256;
    const __bf16* brow = xnT + ((size_t)b * 1024 + n0) * 256;
    auto As = sm.g.A;
    auto Bs = sm.g.B;

    GEMM64_BODY(arow, brow)

    if (m0 < 512) {
        // q/k path: transpose C-tile into LDS [s][c] (bf16x4 packed along c), then
        // coalesced 16B stores (4 lanes -> 64B contiguous) to [b][s][c] layout.
        #pragma unroll
        for (int im = 0; im < 4; im++) {
            #pragma unroll
            for (int in = 0; in < 4; in++) {
                int ob = m0 + wm + im * 16 + quad * 4;
                bf16x4 ov;
                #pragma unroll
                for (int r = 0; r < 4; r++) ov[r] = (__bf16)(acc[im][in][r] + bias[ob + r]);
                *(bf16x4*)&sm.ct[wn + in * 16 + l16][wm + im * 16 + quad * 4] = ov;
            }
        }
        __syncthreads();
        {
            const int rbase = t >> 2, cf = t & 3;
            #pragma unroll
            for (int rr = 0; rr < 2; rr++) {
                int row = rbase + rr * 64;
                int sg = n0 + row;
                __bf16* dst = (m0 < 256) ? &qtr[((size_t)b * 1024 + sg) * 256 + m0]
                                         : &ktr[((size_t)b * 1024 + sg) * 256 + (m0 - 256)];
                #pragma unroll
                for (int u = 0; u < 4; u++) {
                    int colb = cf * 8 + u * 32;
                    *(bf16x8*)&dst[colb] = *(const bf16x8*)&sm.ct[row][colb];
                }
            }
        }
    } else {
        // v path: vbuf is [b][c][t] (c-major) — direct stores (32B chunks per quarter-wave).
        #pragma unroll
        for (int im = 0; im < 4; im++) {
            #pragma unroll
            for (int in = 0; in < 4; in++) {
                int sg = n0 + wn + in * 16 + l16;
                int ob = m0 + wm + im * 16 + quad * 4;
                #pragma unroll
                for (int r = 0; r < 4; r++) {
                    float val = acc[im][in][r] + bias[ob + r];
                    vbuf[((size_t)b * 256 + (ob - 512 + r)) * 1024 + sg] = (__bf16)val;
                }
            }
        }
    }
}

// ---------------- K3: fused flash attention (T14 K/V reg-prefetch + setprio) ----------------
__global__ __launch_bounds__(512, 2) void attn_kernel(const __bf16* __restrict__ qtr,
                                                      const __bf16* __restrict__ ktr,
                                                      const __bf16* __restrict__ vbuf,
                                                      __bf16* __restrict__ aoT) {
    __shared__ __bf16 Kt[2][32][260];   // [t-half][t_local][c]
    __shared__ __bf16 Vs[2][256][36];   // [t-half][c][t_local]
    __shared__ __bf16 Pl[4][32][72];    // [pair][s_local][t64]
    __shared__ float Lred[4][2][32];    // [pair][th][row]
    const int b = blockIdx.x;
    const int tid = threadIdx.x;
    const int wave = tid >> 6, lane = tid & 63, half = lane >> 5, l31 = lane & 31;
    const int pair = wave & 3, th = wave >> 2;
    const int s0 = blockIdx.y * 128 + pair * 32;
    const float kscale = 0.09016844f;   // (1/16) * log2(e); p = exp2(s * kscale)

    bf16x8 aq[16];
    #pragma unroll
    for (int ks = 0; ks < 16; ks++)
        aq[ks] = *(const bf16x8*)&qtr[((size_t)b * 1024 + s0 + l31) * 256 + ks * 16 + half * 8];

    const int k_row = tid >> 3;
    const int k_cb  = (tid & 7) * 8;
    const int v_c   = tid >> 1;
    const int v_th  = tid & 1;
    const size_t kbase = (size_t)b * 1024 * 256;
    const size_t vbase = (size_t)b * 256 * 1024;

    float l_part[16] = {};
    f32x16 o_acc[4] = {};

    // prologue: prefetch tile 0 into registers
    bf16x8 kpre[4], vpre[4];
    #pragma unroll
    for (int u = 0; u < 4; u++) {
        kpre[u] = *(const bf16x8*)&ktr[kbase + (size_t)k_row * 256 + k_cb + u * 64];
        vpre[u] = *(const bf16x8*)&vbuf[vbase + (size_t)v_c * 1024 + v_th * 32 + u * 8];
    }

    for (int it = 0; it < 16; it++) {
        // write current tile from regs (prev iter's closing barrier makes this safe)
        #pragma unroll
        for (int u = 0; u < 4; u++) {
            *(bf16x8*)&Kt[k_row >> 5][k_row & 31][k_cb + u * 64] = kpre[u];
            *(bf16x8*)&Vs[v_th][v_c][u * 8] = vpre[u];
        }
        __syncthreads();
        // T14: issue next tile's global loads NOW — they fly under QK + softmax
        if (it < 15) {
            const int t1 = (it + 1) * 64;
            #pragma unroll
            for (int u = 0; u < 4; u++) {
                kpre[u] = *(const bf16x8*)&ktr[kbase + (size_t)(t1 + k_row) * 256 + k_cb + u * 64];
                vpre[u] = *(const bf16x8*)&vbuf[vbase + (size_t)v_c * 1024 + t1 + v_th * 32 + u * 8];
            }
        }

        f32x16 sc_a = {}, sc_b = {};
        __builtin_amdgcn_s_setprio(1);
        #pragma unroll
        for (int ks = 0; ks < 8; ks++) {
            bf16x8 bk0 = *(const bf16x8*)&Kt[th][l31][ks * 16 + half * 8];
            bf16x8 bk1 = *(const bf16x8*)&Kt[th][l31][(ks + 8) * 16 + half * 8];
            sc_a = MFMA32(aq[ks], bk0, sc_a);
            sc_b = MFMA32(aq[ks + 8], bk1, sc_b);
        }
        __builtin_amdgcn_s_setprio(0);
        #pragma unroll
        for (int r = 0; r < 16; r++) {
            float p = exp2f((sc_a[r] + sc_b[r]) * kscale);
            l_part[r] += p;
            int row = (r & 3) + 8 * (r >> 2) + 4 * half;
            Pl[pair][row][th * 32 + l31] = (__bf16)p;
        }
        __syncthreads();

        bf16x8 ap[4];
        #pragma unroll
        for (int kc = 0; kc < 4; kc++)
            ap[kc] = *(const bf16x8*)&Pl[pair][l31][kc * 16 + half * 8];
        __builtin_amdgcn_s_setprio(1);
        #pragma unroll
        for (int n = 0; n < 4; n++) {
            int c = th * 128 + n * 32 + l31;
            #pragma unroll
            for (int kc = 0; kc < 4; kc++) {
                bf16x8 bv = *(const bf16x8*)&Vs[kc >> 1][c][(kc & 1) * 16 + half * 8];
                o_acc[n] = MFMA32(ap[kc], bv, o_acc[n]);
            }
        }
        __builtin_amdgcn_s_setprio(0);
        __syncthreads();
    }

    float lsum[16];
    #pragma unroll
    for (int r = 0; r < 16; r++) {
        float l = l_part[r];
        #pragma unroll
        for (int m = 16; m > 0; m >>= 1) l += __shfl_xor(l, m, 32);
        lsum[r] = l;
        if (l31 == 0) {
            int row = (r & 3) + 8 * (r >> 2) + 4 * half;
            Lred[pair][th][row] = l;
        }
    }
    __syncthreads();
    #pragma unroll
    for (int r = 0; r < 16; r++) {
        int row = (r & 3) + 8 * (r >> 2) + 4 * half;
        float rinv = 1.0f / (lsum[r] + Lred[pair][1 - th][row]);
        #pragma unroll
        for (int n = 0; n < 4; n++) {
            int c = th * 128 + n * 32 + l31;
            aoT[((size_t)b * 1024 + s0 + row) * 256 + c] = (__bf16)(o_acc[n][r] * rinv);
        }
    }
}

// ---------------- K4: proj GEMM, 128x128 tiles, LDS-staged float4 epilogue ----------------
__global__ __launch_bounds__(256) void proj_gemm(const __bf16* __restrict__ wbf_out,
                                                 const float* __restrict__ bias,
                                                 const __bf16* __restrict__ aoT,
                                                 const float* __restrict__ resid,
                                                 float* __restrict__ Out) {
    __shared__ union {
        struct { __bf16 A[128][72]; __bf16 B[128][72]; } g;   // 36864 B main loop
        float cf[64][132];                                    // 33792 B epilogue (m-half)
    } sm;
    const int b = blockIdx.z;
    const int n0 = blockIdx.x * 128, m0 = blockIdx.y * 128;
    const int t = threadIdx.x;
    const int wave = t >> 6, lane = t & 63, quad = lane >> 4, l16 = lane & 15;
    const int wm = (wave & 1) * 64, wn = (wave >> 1) * 64;
    const __bf16* arow = wbf_out + (size_t)m0 * 256;
    const __bf16* brow = aoT + ((size_t)b * 1024 + n0) * 256;
    auto As = sm.g.A;
    auto Bs = sm.g.B;

    GEMM64_BODY(arow, brow)

    // Epilogue in two m-halves: stage fp32 C into LDS, then 64B-coalesced float4
    // resid-load + Out-store (replaces 64 scalar 4B ld+st pairs per thread).
    for (int h = 0; h < 2; h++) {
        if ((wave & 1) == h) {
            #pragma unroll
            for (int im = 0; im < 4; im++)
                #pragma unroll
                for (int in = 0; in < 4; in++)
                    #pragma unroll
                    for (int r = 0; r < 4; r++)
                        sm.cf[im * 16 + quad * 4 + r][wn + in * 16 + l16] = acc[im][in][r];
        }
        __syncthreads();
        {
            const int rloc = t >> 2, cq = (t & 3) * 4;
            const int o = m0 + h * 64 + rloc;
            const float bo = bias[o];
            const float* rrow = &resid[((size_t)b * 256 + o) * 1024 + n0];
            float* orow = &Out[((size_t)b * 256 + o) * 1024 + n0];
            #pragma unroll
            for (int u = 0; u < 8; u++) {
                int col = cq + u * 16;
                f32x4 cv = *(const f32x4*)&sm.cf[rloc][col];
                float4 rv = *(const float4*)&rrow[col];
                float4 ov;
                ov.x = cv[0] + bo + rv.x;
                ov.y = cv[1] + bo + rv.y;
                ov.z = cv[2] + bo + rv.z;
                ov.w = cv[3] + bo + rv.w;
                *(float4*)&orow[col] = ov;
            }
        }
        __syncthreads();
    }
}

extern "C" void kernel_launch(void* const* d_in, const int* in_sizes, int n_in,
                              void* d_out, int out_size, void* d_ws, size_t ws_size,
                              hipStream_t stream) {
    const float* x    = (const float*)d_in[0];
    const float* gw   = (const float*)d_in[1];
    const float* gb   = (const float*)d_in[2];
    const float* wqkv = (const float*)d_in[3];
    const float* bqkv = (const float*)d_in[4];
    const float* wout = (const float*)d_in[5];
    const float* bout = (const float*)d_in[6];
    float* out = (float*)d_out;

    const size_t T16 = (size_t)32 * 1024 * 256;
    __bf16* xnT  = (__bf16*)d_ws;        // [b][s][c]
    __bf16* qtr  = xnT + T16;            // [b][s][c]
    __bf16* ktr  = qtr + T16;            // [b][t][c]
    __bf16* vbuf = ktr + T16;            // [b][c][t]
    __bf16* aoT  = vbuf + T16;           // [b][s][c]
    __bf16* wbf  = aoT + T16;            // wqkv_bf16 (196608) | wout_bf16 (65536)

    gn_kernel<<<dim3(256), 512, 0, stream>>>(x, gw, gb, xnT, wqkv, wout, wbf);
    qkv_gemm<<<dim3(8, 6, 32), 256, 0, stream>>>(wbf, bqkv, xnT, qtr, ktr, vbuf);
    attn_kernel<<<dim3(32, 8), 512, 0, stream>>>(qtr, ktr, vbuf, aoT);
    proj_gemm<<<dim3(8, 2, 32), 256, 0, stream>>>(wbf + 196608, bout, aoT, x, out);
}

// Round 3
// 192.121 us; speedup vs baseline: 1.0974x; 1.0108x over previous
//
#include <hip/hip_runtime.h>
#include <hip/hip_bf16.h>

// AttentionBlock: GroupNorm(8) -> QKV 1x1 -> softmax attention (hw=1024, c=256) -> proj + residual
// B=32, C=256, H=W=32. Inputs fp32, OUTPUT fp32. Internals bf16 MFMA, fp32 accum.
// R12:
//  - attn: swapped QK^T (mfma(K,Q)) so P has lane=s, regs=t == PV A-fragment layout.
//    V staged with a 4-group slot permutation per 16-t chunk so p-register order matches the
//    MFMA k-slots (no permlane needed). P exchange between th-pairs = 2 b128 w + 2 b128 r
//    (was 16 scalar b16 w + 4 b128 r); l-reduce = 1 scalar + shfl_xor(32) (was 16x5 shfl).
//  - qkv v-path epilogue: LDS-staged [c][t] + 8 coalesced b128 stores (was 64 half-line stores).
// ws: xnT 16MB | qtr 16MB | ktr 16MB | v 16MB | aoT 16MB | wbf 512KB.

typedef __bf16 bf16x8 __attribute__((ext_vector_type(8)));
typedef __bf16 bf16x4 __attribute__((ext_vector_type(4)));
typedef __bf16 bf16x2 __attribute__((ext_vector_type(2)));
typedef float f32x4 __attribute__((ext_vector_type(4)));
typedef float f32x16 __attribute__((ext_vector_type(16)));

#define MFMA16(a, b, c) __builtin_amdgcn_mfma_f32_16x16x32_bf16(a, b, c, 0, 0, 0)
#define MFMA32(a, b, c) __builtin_amdgcn_mfma_f32_32x32x16_bf16(a, b, c, 0, 0, 0)

// ---------------- K1: GroupNorm fp32 [b][c][s] -> bf16 xnT [b][s][c]  (+ fused weight convert) ----------------
__global__ __launch_bounds__(512) void gn_kernel(const float* __restrict__ x,
                                                 const float* __restrict__ gw,
                                                 const float* __restrict__ gb,
                                                 __bf16* __restrict__ xnT,
                                                 const float* __restrict__ wqkv,
                                                 const float* __restrict__ wout,
                                                 __bf16* __restrict__ wbf) {
    __shared__ float red[16];
    __shared__ float stats[2];
    __shared__ __bf16 Lds[512][40];
    const int b = blockIdx.x >> 3, g = blockIdx.x & 7;
    const size_t base = ((size_t)b * 256 + g * 32) * 1024;
    const float* xp = x + base;
    const int t = threadIdx.x;                // 0..511

    // fused wconv: 256 blocks * 512 thr * 2 floats = 262144 (wqkv 196608 | wout 65536)
    {
        int widx = (blockIdx.x * 512 + t) * 2;
        const float* wsrc = (widx < 196608) ? (wqkv + widx) : (wout + (widx - 196608));
        float2 wv = *(const float2*)wsrc;
        bf16x2 wo;
        wo[0] = (__bf16)wv.x; wo[1] = (__bf16)wv.y;
        *(bf16x2*)&wbf[widx] = wo;
    }

    float s = 0.f, s2 = 0.f;
    #pragma unroll
    for (int i = 0; i < 8; i++) {
        int j = i * 512 + t;                  // 8-elem chunk index
        float4 v0 = *(const float4*)(xp + (size_t)j * 8);
        float4 v1 = *(const float4*)(xp + (size_t)j * 8 + 4);
        s  += v0.x + v0.y + v0.z + v0.w + v1.x + v1.y + v1.z + v1.w;
        s2 += v0.x*v0.x + v0.y*v0.y + v0.z*v0.z + v0.w*v0.w
            + v1.x*v1.x + v1.y*v1.y + v1.z*v1.z + v1.w*v1.w;
    }
    #pragma unroll
    for (int o = 32; o > 0; o >>= 1) { s += __shfl_down(s, o, 64); s2 += __shfl_down(s2, o, 64); }
    const int wv = t >> 6;
    if ((t & 63) == 0) { red[wv * 2] = s; red[wv * 2 + 1] = s2; }
    __syncthreads();
    if (t == 0) {
        float ts = 0.f, ts2 = 0.f;
        for (int w = 0; w < 8; w++) { ts += red[w * 2]; ts2 += red[w * 2 + 1]; }
        float mean = ts / 32768.f;
        float var = ts2 / 32768.f - mean * mean;
        stats[0] = mean; stats[1] = rsqrtf(var + 1e-5f);
    }
    __syncthreads();
    const float mean = stats[0], inv = stats[1];

    const int c = t >> 4;                 // 0..31 channel within group
    const int so = (t & 15) * 2;          // s sub-offset (pairs)
    const float ga = gw[g * 32 + c], be = gb[g * 32 + c];

    for (int chunk = 0; chunk < 1024; chunk += 512) {
        #pragma unroll
        for (int i = 0; i < 16; i++) {
            int sl = so + i * 32;
            float2 v = *(const float2*)(xp + (size_t)c * 1024 + chunk + sl);
            Lds[sl][c]     = (__bf16)((v.x - mean) * inv * ga + be);
            Lds[sl + 1][c] = (__bf16)((v.y - mean) * inv * ga + be);
        }
        __syncthreads();
        {
            int sl = t;                   // one s-row per thread
            #pragma unroll
            for (int u = 0; u < 4; u++) {
                bf16x8 vv = *(const bf16x8*)&Lds[sl][u * 8];
                *(bf16x8*)&xnT[((size_t)b * 1024 + chunk + sl) * 256 + g * 32 + u * 8] = vv;
            }
        }
        __syncthreads();
    }
}

// ---------------- shared 128x128 GEMM body, BK=64, register-prefetch pipeline ----------------
#define GEMM64_BODY(ArowBase_, BrowBase_)                                               \
    f32x4 acc[4][4] = {};                                                               \
    const int r_ = t >> 1, kc_ = (t & 1) * 32;                                          \
    bf16x8 pa[4], pb[4];                                                                \
    _Pragma("unroll")                                                                   \
    for (int u = 0; u < 4; u++) {                                                       \
        pa[u] = *(const bf16x8*)&(ArowBase_)[(size_t)r_ * 256 + kc_ + u * 8];           \
        pb[u] = *(const bf16x8*)&(BrowBase_)[(size_t)r_ * 256 + kc_ + u * 8];           \
    }                                                                                   \
    for (int kk = 0; kk < 256; kk += 64) {                                              \
        _Pragma("unroll")                                                               \
        for (int u = 0; u < 4; u++) {                                                   \
            *(bf16x8*)&As[r_][kc_ + u * 8] = pa[u];                                     \
            *(bf16x8*)&Bs[r_][kc_ + u * 8] = pb[u];                                     \
        }                                                                               \
        __syncthreads();                                                                \
        if (kk < 192) {                                                                 \
            _Pragma("unroll")                                                           \
            for (int u = 0; u < 4; u++) {                                               \
                pa[u] = *(const bf16x8*)&(ArowBase_)[(size_t)r_ * 256 + kk + 64 + kc_ + u * 8]; \
                pb[u] = *(const bf16x8*)&(BrowBase_)[(size_t)r_ * 256 + kk + 64 + kc_ + u * 8]; \
            }                                                                           \
        }                                                                               \
        _Pragma("unroll")                                                               \
        for (int kh = 0; kh < 2; kh++) {                                                \
            bf16x8 af[4], bfv[4];                                                       \
            _Pragma("unroll")                                                           \
            for (int im = 0; im < 4; im++)                                              \
                af[im] = *(const bf16x8*)&As[wm + im * 16 + l16][kh * 32 + quad * 8];   \
            _Pragma("unroll")                                                           \
            for (int in = 0; in < 4; in++)                                              \
                bfv[in] = *(const bf16x8*)&Bs[wn + in * 16 + l16][kh * 32 + quad * 8];  \
            _Pragma("unroll")                                                           \
            for (int im = 0; im < 4; im++)                                              \
                _Pragma("unroll")                                                       \
                for (int in = 0; in < 4; in++)                                          \
                    acc[im][in] = MFMA16(af[im], bfv[in], acc[im][in]);                 \
        }                                                                               \
        __syncthreads();                                                                \
    }

// ---------------- K2: QKV GEMM, 128x128 tiles, bf16 weights, LDS-staged epilogues ----------------
__global__ __launch_bounds__(256) void qkv_gemm(const __bf16* __restrict__ wbf,
                                                const float* __restrict__ bias,
                                                const __bf16* __restrict__ xnT,
                                                __bf16* __restrict__ qtr,
                                                __bf16* __restrict__ ktr,
                                                __bf16* __restrict__ vbuf) {
    __shared__ union {
        struct { __bf16 A[128][72]; __bf16 B[128][72]; } g;   // 36864 B main loop
        __bf16 ct[128][136];                                  // 34816 B epilogue
    } sm;
    const int b = blockIdx.z;
    const int n0 = blockIdx.x * 128, m0 = blockIdx.y * 128;
    const int t = threadIdx.x;
    const int wave = t >> 6, lane = t & 63, quad = lane >> 4, l16 = lane & 15;
    const int wm = (wave & 1) * 64, wn = (wave >> 1) * 64;
    const __bf16* arow = wbf + (size_t)m0 * 256;
    const __bf16* brow = xnT + ((size_t)b * 1024 + n0) * 256;
    auto As = sm.g.A;
    auto Bs = sm.g.B;

    GEMM64_BODY(arow, brow)

    if (m0 < 512) {
        // q/k path: transpose C-tile into LDS [s][c], then coalesced bf16x8 stores.
        #pragma unroll
        for (int im = 0; im < 4; im++) {
            #pragma unroll
            for (int in = 0; in < 4; in++) {
                int ob = m0 + wm + im * 16 + quad * 4;
                bf16x4 ov;
                #pragma unroll
                for (int r = 0; r < 4; r++) ov[r] = (__bf16)(acc[im][in][r] + bias[ob + r]);
                *(bf16x4*)&sm.ct[wn + in * 16 + l16][wm + im * 16 + quad * 4] = ov;
            }
        }
        __syncthreads();
        {
            const int rbase = t >> 2, cf = t & 3;
            #pragma unroll
            for (int rr = 0; rr < 2; rr++) {
                int row = rbase + rr * 64;
                int sg = n0 + row;
                __bf16* dst = (m0 < 256) ? &qtr[((size_t)b * 1024 + sg) * 256 + m0]
                                         : &ktr[((size_t)b * 1024 + sg) * 256 + (m0 - 256)];
                #pragma unroll
                for (int u = 0; u < 4; u++) {
                    int colb = cf * 8 + u * 32;
                    *(bf16x8*)&dst[colb] = *(const bf16x8*)&sm.ct[row][colb];
                }
            }
        }
    } else {
        // v path: stage C-tile into LDS as [c][t], then fully-coalesced b128 stores to vbuf [b][c][t].
        #pragma unroll
        for (int im = 0; im < 4; im++) {
            #pragma unroll
            for (int in = 0; in < 4; in++) {
                int cl = wm + im * 16 + quad * 4;
                int tl = wn + in * 16 + l16;
                #pragma unroll
                for (int r = 0; r < 4; r++)
                    sm.ct[cl + r][tl] = (__bf16)(acc[im][in][r] + bias[m0 + cl + r]);
            }
        }
        __syncthreads();
        {
            const int row = t >> 1, tc = (t & 1) * 64;   // c_local row, t-chunk base
            const int cglob = m0 - 512 + row;
            __bf16* dst = &vbuf[((size_t)b * 256 + cglob) * 1024 + n0 + tc];
            #pragma unroll
            for (int u = 0; u < 8; u++)
                *(bf16x8*)&dst[u * 8] = *(const bf16x8*)&sm.ct[row][tc + u * 8];
        }
    }
}

// ---------------- K3: fused flash attention (R12: swapped QK^T, permuted-V slots, slim P exchange) ----------------
__global__ __launch_bounds__(512, 2) void attn_kernel(const __bf16* __restrict__ qtr,
                                                      const __bf16* __restrict__ ktr,
                                                      const __bf16* __restrict__ vbuf,
                                                      __bf16* __restrict__ aoT) {
    __shared__ __bf16 Kt[2][32][260];     // [t-half][t_local][c]
    __shared__ __bf16 Vs[2][256][36];     // [t-half][c][slot]  (slot = permuted t within 16-chunks)
    __shared__ bf16x8 Pl[4][2][2][64];    // [pair][th][chunk][lane] P-fragments for partner wave
    __shared__ float Lred[4][2][32];      // [pair][th][s_local]
    const int b = blockIdx.x;
    const int tid = threadIdx.x;
    const int wave = tid >> 6, lane = tid & 63, half = lane >> 5, l31 = lane & 31;
    const int pair = wave & 3, th = wave >> 2;
    const int s0 = blockIdx.y * 128 + pair * 32;
    const float kscale = 0.09016844f;   // (1/16) * log2(e); p = exp2(s * kscale)

    // Q fragments (B-operand of swapped QK: lane = s-col, elems = c)
    bf16x8 aq[16];
    #pragma unroll
    for (int ks = 0; ks < 16; ks++)
        aq[ks] = *(const bf16x8*)&qtr[((size_t)b * 1024 + s0 + l31) * 256 + ks * 16 + half * 8];

    const int k_row = tid >> 3;
    const int k_cb  = (tid & 7) * 8;
    const int v_c   = tid >> 1;
    const int v_th  = tid & 1;
    const size_t kbase = (size_t)b * 1024 * 256;
    const size_t vbase = (size_t)b * 256 * 1024;

    float l_acc = 0.f;
    f32x16 o_acc[4] = {};

    // prologue: prefetch tile 0 into registers
    bf16x8 kpre[4], vpre[4];
    #pragma unroll
    for (int u = 0; u < 4; u++) {
        kpre[u] = *(const bf16x8*)&ktr[kbase + (size_t)k_row * 256 + k_cb + u * 64];
        vpre[u] = *(const bf16x8*)&vbuf[vbase + (size_t)v_c * 1024 + v_th * 32 + u * 8];
    }

    for (int it = 0; it < 16; it++) {
        // stage K (linear) and V (slot-permuted: within each 16-t chunk, t-groups [0-3,4-7,8-11,12-15]
        // land at slots [0-3,8-11,4-7,12-15] so p-register order matches MFMA k-slots)
        #pragma unroll
        for (int u = 0; u < 4; u++)
            *(bf16x8*)&Kt[k_row >> 5][k_row & 31][k_cb + u * 64] = kpre[u];
        #pragma unroll
        for (int u = 0; u < 4; u++) {
            const bf16x4* hv = (const bf16x4*)&vpre[u];
            const int sbase = (u >> 1) * 16 + (u & 1) * 4;   // 0,4,16,20
            *(bf16x4*)&Vs[v_th][v_c][sbase]     = hv[0];
            *(bf16x4*)&Vs[v_th][v_c][sbase + 8] = hv[1];
        }
        __syncthreads();
        // T14: issue next tile's global loads NOW — they fly under QK + softmax
        if (it < 15) {
            const int t1 = (it + 1) * 64;
            #pragma unroll
            for (int u = 0; u < 4; u++) {
                kpre[u] = *(const bf16x8*)&ktr[kbase + (size_t)(t1 + k_row) * 256 + k_cb + u * 64];
                vpre[u] = *(const bf16x8*)&vbuf[vbase + (size_t)v_c * 1024 + t1 + v_th * 32 + u * 8];
            }
        }

        // swapped QK^T: A = K (lane = t-row), B = Q (lane = s-col) -> C: regs = t, lane = s
        f32x16 sc_a = {}, sc_b = {};
        __builtin_amdgcn_s_setprio(1);
        #pragma unroll
        for (int ks = 0; ks < 8; ks++) {
            bf16x8 bk0 = *(const bf16x8*)&Kt[th][l31][ks * 16 + half * 8];
            bf16x8 bk1 = *(const bf16x8*)&Kt[th][l31][(ks + 8) * 16 + half * 8];
            sc_a = MFMA32(bk0, aq[ks], sc_a);
            sc_b = MFMA32(bk1, aq[ks + 8], sc_b);
        }
        __builtin_amdgcn_s_setprio(0);

        // softmax partial + P fragments (lane = s, regs = t -> direct PV A-operand)
        bf16x8 pf0, pf1;
        #pragma unroll
        for (int r = 0; r < 8; r++) {
            float p = exp2f((sc_a[r] + sc_b[r]) * kscale);
            l_acc += p;
            pf0[r] = (__bf16)p;
        }
        #pragma unroll
        for (int r = 8; r < 16; r++) {
            float p = exp2f((sc_a[r] + sc_b[r]) * kscale);
            l_acc += p;
            pf1[r - 8] = (__bf16)p;
        }
        Pl[pair][th][0][lane] = pf0;
        Pl[pair][th][1][lane] = pf1;
        __syncthreads();
        bf16x8 pp0 = Pl[pair][1 - th][0][lane];
        bf16x8 pp1 = Pl[pair][1 - th][1][lane];

        bf16x8 ap[4];
        if (th == 0) { ap[0] = pf0; ap[1] = pf1; ap[2] = pp0; ap[3] = pp1; }
        else         { ap[0] = pp0; ap[1] = pp1; ap[2] = pf0; ap[3] = pf1; }

        __builtin_amdgcn_s_setprio(1);
        #pragma unroll
        for (int n = 0; n < 4; n++) {
            int c = th * 128 + n * 32 + l31;
            #pragma unroll
            for (int kc = 0; kc < 4; kc++) {
                bf16x8 bv = *(const bf16x8*)&Vs[kc >> 1][c][(kc & 1) * 16 + half * 8];
                o_acc[n] = MFMA32(ap[kc], bv, o_acc[n]);
            }
        }
        __builtin_amdgcn_s_setprio(0);
        __syncthreads();
    }

    // l reduction: combine lane-halves (same s), then th-pairs via LDS
    l_acc += __shfl_xor(l_acc, 32, 64);
    if (lane < 32) Lred[pair][th][l31] = l_acc;
    __syncthreads();
    #pragma unroll
    for (int r = 0; r < 16; r++) {
        int row = (r & 3) + 8 * (r >> 2) + 4 * half;
        float rinv = 1.0f / (Lred[pair][0][row] + Lred[pair][1][row]);
        #pragma unroll
        for (int n = 0; n < 4; n++) {
            int c = th * 128 + n * 32 + l31;
            aoT[((size_t)b * 1024 + s0 + row) * 256 + c] = (__bf16)(o_acc[n][r] * rinv);
        }
    }
}

// ---------------- K4: proj GEMM, 128x128 tiles, LDS-staged float4 epilogue ----------------
__global__ __launch_bounds__(256) void proj_gemm(const __bf16* __restrict__ wbf_out,
                                                 const float* __restrict__ bias,
                                                 const __bf16* __restrict__ aoT,
                                                 const float* __restrict__ resid,
                                                 float* __restrict__ Out) {
    __shared__ union {
        struct { __bf16 A[128][72]; __bf16 B[128][72]; } g;   // 36864 B main loop
        float cf[64][132];                                    // 33792 B epilogue (m-half)
    } sm;
    const int b = blockIdx.z;
    const int n0 = blockIdx.x * 128, m0 = blockIdx.y * 128;
    const int t = threadIdx.x;
    const int wave = t >> 6, lane = t & 63, quad = lane >> 4, l16 = lane & 15;
    const int wm = (wave & 1) * 64, wn = (wave >> 1) * 64;
    const __bf16* arow = wbf_out + (size_t)m0 * 256;
    const __bf16* brow = aoT + ((size_t)b * 1024 + n0) * 256;
    auto As = sm.g.A;
    auto Bs = sm.g.B;

    GEMM64_BODY(arow, brow)

    for (int h = 0; h < 2; h++) {
        if ((wave & 1) == h) {
            #pragma unroll
            for (int im = 0; im < 4; im++)
                #pragma unroll
                for (int in = 0; in < 4; in++)
                    #pragma unroll
                    for (int r = 0; r < 4; r++)
                        sm.cf[im * 16 + quad * 4 + r][wn + in * 16 + l16] = acc[im][in][r];
        }
        __syncthreads();
        {
            const int rloc = t >> 2, cq = (t & 3) * 4;
            const int o = m0 + h * 64 + rloc;
            const float bo = bias[o];
            const float* rrow = &resid[((size_t)b * 256 + o) * 1024 + n0];
            float* orow = &Out[((size_t)b * 256 + o) * 1024 + n0];
            #pragma unroll
            for (int u = 0; u < 8; u++) {
                int col = cq + u * 16;
                f32x4 cv = *(const f32x4*)&sm.cf[rloc][col];
                float4 rv = *(const float4*)&rrow[col];
                float4 ov;
                ov.x = cv[0] + bo + rv.x;
                ov.y = cv[1] + bo + rv.y;
                ov.z = cv[2] + bo + rv.z;
                ov.w = cv[3] + bo + rv.w;
                *(float4*)&orow[col] = ov;
            }
        }
        __syncthreads();
    }
}

extern "C" void kernel_launch(void* const* d_in, const int* in_sizes, int n_in,
                              void* d_out, int out_size, void* d_ws, size_t ws_size,
                              hipStream_t stream) {
    const float* x    = (const float*)d_in[0];
    const float* gw   = (const float*)d_in[1];
    const float* gb   = (const float*)d_in[2];
    const float* wqkv = (const float*)d_in[3];
    const float* bqkv = (const float*)d_in[4];
    const float* wout = (const float*)d_in[5];
    const float* bout = (const float*)d_in[6];
    float* out = (float*)d_out;

    const size_t T16 = (size_t)32 * 1024 * 256;
    __bf16* xnT  = (__bf16*)d_ws;        // [b][s][c]
    __bf16* qtr  = xnT + T16;            // [b][s][c]
    __bf16* ktr  = qtr + T16;            // [b][t][c]
    __bf16* vbuf = ktr + T16;            // [b][c][t]
    __bf16* aoT  = vbuf + T16;           // [b][s][c]
    __bf16* wbf  = aoT + T16;            // wqkv_bf16 (196608) | wout_bf16 (65536)

    gn_kernel<<<dim3(256), 512, 0, stream>>>(x, gw, gb, xnT, wqkv, wout, wbf);
    qkv_gemm<<<dim3(8, 6, 32), 256, 0, stream>>>(wbf, bqkv, xnT, qtr, ktr, vbuf);
    attn_kernel<<<dim3(32, 8), 512, 0, stream>>>(qtr, ktr, vbuf, aoT);
    proj_gemm<<<dim3(8, 2, 32), 256, 0, stream>>>(wbf + 196608, bout, aoT, x, out);
}